// Round 5
// baseline (929.305 us; speedup 1.0000x reference)
//
#include <hip/hip_runtime.h>

#define N_ENT 200000
#define N_USR 100000
#define NT3   700000      // N_ENT*3 virt-segments + N_USR user segments
#define UKEY0 600000      // first user segment key
#define DIM 64
#define NE 1500000
#define NI_ 1000000
#define NTE 2500000       // NE + NI_
#define NREL1 10
#define NVIRT 3
#define EPSF 1e-12f
#define SCAN_B 1024
#define CE 4              // cached rows per (entity,virt) segment
#define RU 12             // cached rows per user segment

// ---------- float4 helpers ----------
__device__ __forceinline__ float4 f4_zero() { return make_float4(0.f, 0.f, 0.f, 0.f); }
__device__ __forceinline__ float4 f4_add(float4 a, float4 b) {
    return make_float4(a.x + b.x, a.y + b.y, a.z + b.z, a.w + b.w);
}
__device__ __forceinline__ float4 f4_scale(float s, float4 a) {
    return make_float4(s * a.x, s * a.y, s * a.z, s * a.w);
}
__device__ __forceinline__ float4 f4_fma(float s, float4 a, float4 b) {
    return make_float4(fmaf(s, a.x, b.x), fmaf(s, a.y, b.y), fmaf(s, a.z, b.z), fmaf(s, a.w, b.w));
}
__device__ __forceinline__ float f4_dot(float4 a, float4 b) {
    return a.x * b.x + a.y * b.y + a.z * b.z + a.w * b.w;
}
__device__ __forceinline__ float red16(float v) {
    v += __shfl_xor(v, 1, 16);
    v += __shfl_xor(v, 2, 16);
    v += __shfl_xor(v, 4, 16);
    v += __shfl_xor(v, 8, 16);
    return v;
}
__device__ __forceinline__ float4 squash4(float4 u, float sq) {
    float n = sqrtf(sq);
    float s = sq / ((sq + 1.f) * fmaxf(n, EPSF));
    return f4_scale(s, u);
}
// bf16 row gather: row p is 16 x uint2 (4 bf16 per lane), convert to fp32
__device__ __forceinline__ float4 ldrow(const uint2* __restrict__ tb, int p, int lane) {
    uint2 w = tb[p * 16 + lane];
    float4 x;
    x.x = __uint_as_float(w.x << 16);
    x.y = __uint_as_float(w.x & 0xFFFF0000u);
    x.z = __uint_as_float(w.y << 16);
    x.w = __uint_as_float(w.y & 0xFFFF0000u);
    return x;
}
// pack two fp32 -> one dword of 2 bf16 (RNE)
__device__ __forceinline__ unsigned int bf2(float a, float b) {
    unsigned int ua = __float_as_uint(a); ua = ua + 0x7FFFu + ((ua >> 16) & 1u);
    unsigned int ub = __float_as_uint(b); ub = ub + 0x7FFFu + ((ub >> 16) & 1u);
    return (ua >> 16) | (ub & 0xFFFF0000u);
}

// ---------- fp32 -> bf16 table convert ----------
__global__ void k_tobf16(const float* __restrict__ src, uint2* __restrict__ dst, int n16) {
    int i = blockIdx.x * blockDim.x + threadIdx.x;
    if (i < n16) {
        float4 v = ((const float4*)src)[i];
        dst[i] = make_uint2(bf2(v.x, v.y), bf2(v.z, v.w));
    }
}

// ---------- prep: relation->virt argmax + per-hop softmax ----------
__global__ void k_prep(const float* __restrict__ rw, const float* __restrict__ lat,
                       const float* __restrict__ aw, int* __restrict__ remap,
                       float* __restrict__ wsoft) {
    int t = threadIdx.x;
    if (t < NREL1) {
        float best = -3.4e38f; int bi = 0;
        for (int j = 0; j < NVIRT; j++) {
            float s = 0.f;
            for (int d = 0; d < DIM; d++) s += rw[t * DIM + d] * lat[j * DIM + d];
            if (s > best) { best = s; bi = j; }
        }
        remap[t] = bi;
    }
    if (t >= 32 && t < 34) {
        int h = t - 32;
        float a0 = aw[h * 3 + 0], a1 = aw[h * 3 + 1], a2 = aw[h * 3 + 2];
        float m = fmaxf(a0, fmaxf(a1, a2));
        float e0 = expf(a0 - m), e1 = expf(a1 - m), e2 = expf(a2 - m);
        float s = e0 + e1 + e2;
        wsoft[h * 3 + 0] = e0 / s; wsoft[h * 3 + 1] = e1 / s; wsoft[h * 3 + 2] = e2 / s;
    }
}

// ---------- combined CSR build ----------
__global__ void k_count_all(const int* __restrict__ head, const int* __restrict__ etype,
                            const int* __restrict__ remap, const int* __restrict__ uidx,
                            int* __restrict__ cnt) {
    int i = blockIdx.x * blockDim.x + threadIdx.x;
    if (i < NE) {
        int key = head[i] * 3 + remap[etype[i] - 1];
        atomicAdd(&cnt[key], 1);
    } else if (i < NTE) {
        atomicAdd(&cnt[UKEY0 + uidx[i - NE]], 1);
    }
}

__global__ void k_scan1(const int* __restrict__ in, int* __restrict__ excl,
                        int* __restrict__ bsum, int n) {
    __shared__ int s[SCAN_B];
    int tid = threadIdx.x, gid = blockIdx.x * SCAN_B + tid;
    int v = (gid < n) ? in[gid] : 0;
    s[tid] = v; __syncthreads();
    for (int off = 1; off < SCAN_B; off <<= 1) {
        int t = 0;
        if (tid >= off) t = s[tid - off];
        __syncthreads();
        s[tid] += t;
        __syncthreads();
    }
    if (gid < n) excl[gid] = s[tid] - v;
    if (tid == SCAN_B - 1) bsum[blockIdx.x] = s[tid];
}

__global__ void k_scan2(int* __restrict__ bsum, int nb) {
    __shared__ int s[SCAN_B];
    int tid = threadIdx.x;
    int v = (tid < nb) ? bsum[tid] : 0;
    s[tid] = v; __syncthreads();
    for (int off = 1; off < SCAN_B; off <<= 1) {
        int t = 0;
        if (tid >= off) t = s[tid - off];
        __syncthreads();
        s[tid] += t;
        __syncthreads();
    }
    if (tid < nb) bsum[tid] = s[tid] - v;
}

__global__ void k_scan3(const int* __restrict__ excl, const int* __restrict__ bsum,
                        const int* __restrict__ cnt, int* __restrict__ rp,
                        int* __restrict__ cur, int n) {
    int gid = blockIdx.x * SCAN_B + threadIdx.x;
    if (gid < n) {
        int v = excl[gid] + bsum[blockIdx.x];
        rp[gid] = v;
        cur[gid] = v;
        if (gid == n - 1) rp[n] = v + cnt[gid];
    }
}

__global__ void k_scatter_all(const int* __restrict__ head, const int* __restrict__ tail,
                              const int* __restrict__ etype, const int* __restrict__ remap,
                              const int* __restrict__ uidx, const int* __restrict__ iidx,
                              int* __restrict__ cur, int* __restrict__ sorted) {
    int i = blockIdx.x * blockDim.x + threadIdx.x;
    if (i < NE) {
        int key = head[i] * 3 + remap[etype[i] - 1];
        int pos = atomicAdd(&cur[key], 1);
        sorted[pos] = tail[i];
    } else if (i < NTE) {
        int j = i - NE;
        int pos = atomicAdd(&cur[UKEY0 + uidx[j]], 1);
        sorted[pos] = iidx[j];
    }
}

// ---------- merged per-hop LWS ----------
#define NBLK_E (N_ENT / 16)   // 12500
#define NBLK_U (N_USR / 16)   // 6250

// per-virt LWS macro (keeps xc arrays in registers; no pointer indirection)
#define HIDX(CI) ((CI) < 16 ? __shfl(myp, (CI), 16) : sorted[b0 + (CI)])
#define VIRT_LWS(XC, OFF, DEG, V)                                                   \
{                                                                                   \
    float inv = 1.f / fmaxf((float)(DEG), 1.f);                                     \
    float4 acc = f4_zero();                                                         \
    _Pragma("unroll")                                                               \
    for (int r = 0; r < CE; r++) if (r < (DEG)) acc = f4_add(acc, XC[r]);           \
    for (int r = CE; r < (DEG); r++) {                                              \
        int p = HIDX((OFF) + r);                                                    \
        acc = f4_add(acc, ldrow(tb, p, lane));                                      \
    }                                                                               \
    float4 u = f4_scale(inv, acc);                                                  \
    float sq = red16(f4_dot(u, u));                                                 \
    float4 u1 = f4_add(squash4(u, sq), eh);                                         \
    acc = f4_zero();                                                                \
    _Pragma("unroll")                                                               \
    for (int r = 0; r < CE; r++) if (r < (DEG)) {                                   \
        float4 x = XC[r];                                                           \
        float dd = red16(f4_dot(u1, x));                                            \
        if (lane == (V) * 4 + r) d1all = dd;                                        \
        acc = f4_fma(dd, x, acc);                                                   \
    }                                                                               \
    for (int r = CE; r < (DEG); r++) {                                              \
        int p = HIDX((OFF) + r);                                                    \
        float4 x = ldrow(tb, p, lane);                                              \
        float dd = red16(f4_dot(u1, x));                                            \
        acc = f4_fma(dd, x, acc);                                                   \
    }                                                                               \
    u = f4_scale(inv, acc);                                                         \
    sq = red16(f4_dot(u, u));                                                       \
    float4 u2 = f4_add(squash4(u, sq), eh);                                         \
    acc = f4_zero();                                                                \
    _Pragma("unroll")                                                               \
    for (int r = 0; r < CE; r++) if (r < (DEG)) {                                   \
        float4 x = XC[r];                                                           \
        float d2 = red16(f4_dot(u2, x));                                            \
        float dd = __shfl(d1all, (V) * 4 + r, 16);                                  \
        acc = f4_fma(dd * dd * d2, x, acc);                                         \
    }                                                                               \
    for (int r = CE; r < (DEG); r++) {                                              \
        int p = HIDX((OFF) + r);                                                    \
        float4 x = ldrow(tb, p, lane);                                              \
        float d2 = red16(f4_dot(u2, x));                                            \
        float dd = red16(f4_dot(u1, x));                                            \
        acc = f4_fma(dd * dd * d2, x, acc);                                         \
    }                                                                               \
    agg = f4_fma(wsoft[hop * 3 + (V)] * inv, acc, agg);                             \
}

__global__ __launch_bounds__(256, 5) void k_hop(
    const float* __restrict__ ent32,      // fp32 table (own rows)
    const uint2* __restrict__ tb,         // bf16 gather table
    const float* __restrict__ usr,
    const int* __restrict__ rp, const int* __restrict__ sorted,
    const float* __restrict__ wsoft, int hop,
    float* __restrict__ ent_next, uint2* __restrict__ entb_next,
    float* __restrict__ usr_next,
    int do_store, int first,
    float* __restrict__ outE, float* __restrict__ outU)
{
    int lane = threadIdx.x & 15;

    if (blockIdx.x < NBLK_E) {
        // ================= entity path =================
        int g = blockIdx.x * 16 + (threadIdx.x >> 4);
        float4 eh = ((const float4*)ent32)[g * 16 + lane];
        int b0 = rp[3 * g], b1 = rp[3 * g + 1], b2 = rp[3 * g + 2], b3 = rp[3 * g + 3];
        int d0 = b1 - b0, d1v = b2 - b1, d2v = b3 - b2;
        int degtot = b3 - b0;
        int hcap = (degtot < 16) ? degtot : 16;
        int o1 = d0, o2 = d0 + d1v;

        int myp = (lane < hcap) ? sorted[b0 + lane] : 0;

        // prefetch per-virt row caches (up to 12 independent gathers in flight)
        float4 xc0[CE], xc1[CE], xc2[CE];
        #pragma unroll
        for (int r = 0; r < CE; r++) if (r < d0)  xc0[r] = ldrow(tb, HIDX(r), lane);
        #pragma unroll
        for (int r = 0; r < CE; r++) if (r < d1v) xc1[r] = ldrow(tb, HIDX(o1 + r), lane);
        #pragma unroll
        for (int r = 0; r < CE; r++) if (r < d2v) xc2[r] = ldrow(tb, HIDX(o2 + r), lane);

        float4 agg = f4_zero();
        float d1all = 0.f;
        VIRT_LWS(xc0, 0, d0, 0)
        VIRT_LWS(xc1, o1, d1v, 1)
        VIRT_LWS(xc2, o2, d2v, 2)

        agg = f4_add(agg, eh);    // sum_v w_v * eh = eh
        float sq = red16(f4_dot(agg, agg));
        float nn = sqrtf(sq);
        float4 en = f4_scale(1.f / fmaxf(nn, EPSF), agg);
        if (do_store) {
            ((float4*)ent_next)[g * 16 + lane] = en;
            entb_next[g * 16 + lane] = make_uint2(bf2(en.x, en.y), bf2(en.z, en.w));
        }
        float4* outv = (float4*)outE;
        float4 base = first ? eh : outv[g * 16 + lane];
        outv[g * 16 + lane] = f4_add(base, en);
    } else {
        // ================= user path =================
        int gu = (blockIdx.x - NBLK_E) * 16 + (threadIdx.x >> 4);
        int s = rp[UKEY0 + gu], e = rp[UKEY0 + gu + 1];
        int deg = e - s;
        float4 uh = ((const float4*)usr)[gu * 16 + lane];
        float inv = 1.f / fmaxf((float)deg, 1.f);

        int deg16 = (deg < 16) ? deg : 16;
        int myp = (lane < deg16) ? sorted[s + lane] : 0;

        float4 xc[RU];
        float4 acc = f4_zero();
        // iter 0 + cache fill
        #pragma unroll
        for (int r = 0; r < RU; r++) {
            if (r < deg) {
                int p = __shfl(myp, r, 16);
                float4 x = ldrow(tb, p, lane);
                xc[r] = x;
                acc = f4_add(acc, x);
            }
        }
        for (int r = RU; r < deg; r++) {
            int p = (r < 16) ? __shfl(myp, r, 16) : sorted[s + r];
            acc = f4_add(acc, ldrow(tb, p, lane));
        }
        float4 u = f4_scale(inv, acc);
        float sq = red16(f4_dot(u, u));
        float4 u1 = f4_add(squash4(u, sq), uh);

        // iter 1
        acc = f4_zero();
        #pragma unroll
        for (int r = 0; r < RU; r++) {
            if (r < deg) {
                float4 x = xc[r];
                acc = f4_fma(red16(f4_dot(u1, x)), x, acc);
            }
        }
        for (int r = RU; r < deg; r++) {
            int p = (r < 16) ? __shfl(myp, r, 16) : sorted[s + r];
            float4 x = ldrow(tb, p, lane);
            acc = f4_fma(red16(f4_dot(u1, x)), x, acc);
        }
        u = f4_scale(inv, acc);
        sq = red16(f4_dot(u, u));
        float4 u2 = f4_add(squash4(u, sq), uh);

        // iter 2
        acc = f4_zero();
        #pragma unroll
        for (int r = 0; r < RU; r++) {
            if (r < deg) {
                float4 x = xc[r];
                acc = f4_fma(red16(f4_dot(u2, x)), x, acc);
            }
        }
        for (int r = RU; r < deg; r++) {
            int p = (r < 16) ? __shfl(myp, r, 16) : sorted[s + r];
            float4 x = ldrow(tb, p, lane);
            acc = f4_fma(red16(f4_dot(u2, x)), x, acc);
        }
        float4 u3 = f4_add(f4_scale(inv, acc), uh);
        sq = red16(f4_dot(u3, u3));
        float nn = sqrtf(sq);
        float4 un = f4_scale(1.f / fmaxf(nn, EPSF), u3);
        if (do_store) ((float4*)usr_next)[gu * 16 + lane] = un;
        float4* outv = (float4*)outU;
        float4 base = first ? uh : outv[gu * 16 + lane];
        outv[gu * 16 + lane] = f4_add(base, un);
    }
}

// ---------- launch ----------
extern "C" void kernel_launch(void* const* d_in, const int* in_sizes, int n_in,
                              void* d_out, int out_size, void* d_ws, size_t ws_size,
                              hipStream_t stream)
{
    const float* entity_emb = (const float*)d_in[0];
    const float* user_emb   = (const float*)d_in[1];
    const float* latent     = (const float*)d_in[2];
    const float* rel_w      = (const float*)d_in[3];
    const float* agg_w      = (const float*)d_in[4];
    const int* edge_index   = (const int*)d_in[5];
    const int* edge_type    = (const int*)d_in[6];
    const int* user_index   = (const int*)d_in[7];
    const int* item_index   = (const int*)d_in[8];
    float* out = (float*)d_out;

    char* ws = (char*)d_ws;
    size_t off = 0;
    auto alloc = [&](size_t bytes) -> void* {
        void* p = ws + off;
        off += (bytes + 255) / 256 * 256;
        return p;
    };
    float* entA  = (float*)alloc((size_t)N_ENT * DIM * 4);   // fp32 next entity table
    uint2* entB0 = (uint2*)alloc((size_t)N_ENT * DIM * 2);   // bf16 table hop0
    uint2* entB1 = (uint2*)alloc((size_t)N_ENT * DIM * 2);   // bf16 table hop1
    float* usrA  = (float*)alloc((size_t)N_USR * DIM * 4);
    float* wsoft = (float*)alloc(8 * 4);
    int* remap   = (int*)alloc(16 * 4);
    int* cnt     = (int*)alloc((size_t)NT3 * 4);
    int* rp      = (int*)alloc((size_t)(NT3 + 1) * 4);
    int* cur     = (int*)alloc((size_t)NT3 * 4);
    int* excl    = (int*)alloc((size_t)NT3 * 4);
    int* bsum    = (int*)alloc(1024 * 4);
    int* sorted  = (int*)alloc((size_t)NTE * 4);

    const int* head = edge_index;
    const int* tail = edge_index + NE;

    hipMemsetAsync(cnt, 0, (size_t)NT3 * 4, stream);

    k_prep<<<1, 64, 0, stream>>>(rel_w, latent, agg_w, remap, wsoft);
    k_tobf16<<<(N_ENT * 16 + 255) / 256, 256, 0, stream>>>(entity_emb, entB0, N_ENT * 16);

    k_count_all<<<(NTE + 255) / 256, 256, 0, stream>>>(head, edge_type, remap, user_index, cnt);

    int nb = (NT3 + SCAN_B - 1) / SCAN_B;   // 684 <= 1024
    k_scan1<<<nb, SCAN_B, 0, stream>>>(cnt, excl, bsum, NT3);
    k_scan2<<<1, SCAN_B, 0, stream>>>(bsum, nb);
    k_scan3<<<nb, SCAN_B, 0, stream>>>(excl, bsum, cnt, rp, cur, NT3);

    k_scatter_all<<<(NTE + 255) / 256, 256, 0, stream>>>(
        head, tail, edge_type, remap, user_index, item_index, cur, sorted);

    const float* ec32 = entity_emb;
    const uint2* ecb  = entB0;
    const float* uc   = user_emb;
    for (int hop = 0; hop < 2; hop++) {
        int do_store = (hop == 0);
        int first = (hop == 0);
        k_hop<<<NBLK_E + NBLK_U, 256, 0, stream>>>(
            ec32, ecb, uc, rp, sorted, wsoft, hop,
            entA, entB1, usrA, do_store, first,
            out, out + (size_t)N_ENT * DIM);
        ec32 = entA;
        ecb  = entB1;
        uc   = usrA;
    }
}